// Round 8
// baseline (218.982 us; speedup 1.0000x reference)
//
#include <hip/hip_runtime.h>

#define NB 4
#define NT 2048
#define ND 512
#define NH 8
#define NHD 64

typedef __attribute__((ext_vector_type(4))) float f32x4;
typedef __attribute__((ext_vector_type(8))) short bf16x8;
typedef __attribute__((ext_vector_type(4))) short bf16x4;
typedef __attribute__((ext_vector_type(4))) unsigned int u32x4;
typedef __attribute__((ext_vector_type(2))) unsigned int u32x2;

__device__ __forceinline__ unsigned short f2bf(float f) {
    unsigned u = __builtin_bit_cast(unsigned, f);
    u += 0x7FFFu + ((u >> 16) & 1u);
    return (unsigned short)(u >> 16);
}
__device__ __forceinline__ float bf2f(unsigned short h) {
    unsigned u = ((unsigned)h) << 16;
    return __builtin_bit_cast(float, u);
}
__device__ __forceinline__ float exp2_fast(float x) {
    float r;
    asm("v_exp_f32 %0, %1" : "=v"(r) : "v"(x));
    return r;
}
__device__ __forceinline__ unsigned cvt_pk_bf16(float lo, float hi) {
    unsigned r;
    asm("v_cvt_pk_bf16_f32 %0, %1, %2" : "=v"(r) : "v"(lo), "v"(hi));
    return r;
}

#define GLOAD16(g, s)                                                          \
    __builtin_amdgcn_global_load_lds(                                          \
        (const __attribute__((address_space(1))) unsigned int*)(g),            \
        (__attribute__((address_space(3))) unsigned int*)(s), 16, 0, 0)

// ---------------- fused prep: cvt(x) + tr(Wqkv) + tr(Wout) ----------------
__global__ __launch_bounds__(256) void k_prep(const float* __restrict__ x,
                                              const float* __restrict__ Wqkv,
                                              const float* __restrict__ Wout,
                                              unsigned short* __restrict__ xb,
                                              unsigned short* __restrict__ wqkvt,
                                              unsigned short* __restrict__ woutt) {
    __shared__ unsigned short tile[32][33];
    int id = blockIdx.x;
    if (id < 2048) {
        int i = id * 256 + threadIdx.x;
        const float* p = x + (long)i * 8;
        f32x4 a = *(const f32x4*)p;
        f32x4 b = *(const f32x4*)(p + 4);
        bf16x8 o;
#pragma unroll
        for (int e = 0; e < 4; e++) {
            o[e] = (short)f2bf(a[e]);
            o[e + 4] = (short)f2bf(b[e]);
        }
        *(bf16x8*)(xb + (long)i * 8) = o;
        return;
    }
    const float* in;
    unsigned short* out;
    int R, C, bx, by;
    if (id < 2816) {
        int t = id - 2048;
        in = Wqkv; out = wqkvt; R = 512; C = 1536;
        bx = t % 48; by = t / 48;
    } else {
        int t = id - 2816;
        in = Wout; out = woutt; R = 512; C = 512;
        bx = t % 16; by = t / 16;
    }
    int c0 = bx * 32, r0 = by * 32;
    int tx = threadIdx.x & 31, ty = threadIdx.x >> 5;
#pragma unroll
    for (int j = 0; j < 32; j += 8)
        tile[ty + j][tx] = f2bf(in[(long)(r0 + ty + j) * C + c0 + tx]);
    __syncthreads();
#pragma unroll
    for (int j = 0; j < 32; j += 8)
        out[(long)(c0 + ty + j) * R + r0 + tx] = tile[tx][ty + j];
}

// ---------------- bf16 GEMM1: qkv = xb * Wqkv^T, scatter epilogue ----------
__global__ __launch_bounds__(256) void k_gemm1(const unsigned short* __restrict__ A,
                                               const unsigned short* __restrict__ Bt,
                                               unsigned short* __restrict__ q,
                                               unsigned short* __restrict__ kk_,
                                               unsigned short* __restrict__ vt,
                                               int K, int N) {
    __shared__ unsigned short Al[128 * 64];
    __shared__ unsigned short Bl[128 * 64];
    int id = blockIdx.x;
    int xcd = id & 7, s = id >> 3;
    int ytile = (s & 7) * 8 + xcd;
    int xtile = s >> 3;
    int m0 = ytile * 128, n0 = xtile * 128;
    int tid = threadIdx.x;
    int w = tid >> 6, l = tid & 63;
    int wm = (w >> 1) * 64, wn = (w & 1) * 64;
    int lr = l & 15, lg = l >> 4;
    int lrow8 = l >> 3, lch = l & 7;
    int chg = lch ^ lrow8;

    f32x4 acc[4][4];
#pragma unroll
    for (int i = 0; i < 4; i++)
#pragma unroll
        for (int j = 0; j < 4; j++) acc[i][j] = (f32x4){0.f, 0.f, 0.f, 0.f};

    for (int k0 = 0; k0 < K; k0 += 64) {
        __syncthreads();
#pragma unroll
        for (int p = 0; p < 4; p++) {
            int br = p * 32 + w * 8;
            int row = br + lrow8;
            GLOAD16(A + (long)(m0 + row) * K + k0 + chg * 8, &Al[br * 64]);
            GLOAD16(Bt + (long)(n0 + row) * K + k0 + chg * 8, &Bl[br * 64]);
        }
        __syncthreads();
#pragma unroll
        for (int kc = 0; kc < 2; kc++) {
            bf16x8 af[4], bff[4];
#pragma unroll
            for (int i = 0; i < 4; i++) {
                int row = wm + i * 16 + lr;
                int ch = (kc * 4 + lg) ^ (row & 7);
                af[i] = *(const bf16x8*)(Al + row * 64 + ch * 8);
                int rowb = wn + i * 16 + lr;
                int chb = (kc * 4 + lg) ^ (rowb & 7);
                bff[i] = *(const bf16x8*)(Bl + rowb * 64 + chb * 8);
            }
#pragma unroll
            for (int i = 0; i < 4; i++)
#pragma unroll
                for (int j = 0; j < 4; j++)
                    acc[i][j] = __builtin_amdgcn_mfma_f32_16x16x32_bf16(af[i], bff[j], acc[i][j], 0, 0, 0);
        }
    }

#pragma unroll
    for (int i = 0; i < 4; i++)
#pragma unroll
        for (int j = 0; j < 4; j++) {
            int m = m0 + wm + i * 16 + lg * 4;
            int col = n0 + wn + j * 16 + lr;
            int sel = col >> 9;
            int cc = col & 511;
            int h = cc >> 6, hd = cc & 63;
            int b = m >> 11, t = m & 2047;
            long bh = (long)(b * NH + h);
            if (sel == 0) {
#pragma unroll
                for (int r = 0; r < 4; r++)
                    q[(bh * NT + t + r) * NHD + hd] = f2bf(acc[i][j][r]);
            } else if (sel == 1) {
#pragma unroll
                for (int r = 0; r < 4; r++)
                    kk_[(bh * NT + t + r) * NHD + hd] = f2bf(acc[i][j][r]);
            } else {
                bf16x4 pk;
#pragma unroll
                for (int r = 0; r < 4; r++) pk[r] = (short)f2bf(acc[i][j][r]);
                *(bf16x4*)(vt + (bh * NHD + hd) * NT + t) = pk;
            }
        }
}

// ---------------- bf16 GEMM2: out = yb * Wout^T, split-K=2, atomic ---------
// 64x128 tile x 2 k-halves -> 1024 blocks (4/CU). d_out zeroed by memset;
// each k-half atomicAdds its partial (device-scope, cross-XCD safe).
__global__ __launch_bounds__(256) void k_gemm2(const unsigned short* __restrict__ A,
                                               const unsigned short* __restrict__ Bt,
                                               float* __restrict__ outf,
                                               int K, int N) {
    __shared__ unsigned short Al[2][64 * 64];
    __shared__ unsigned short Bl[2][128 * 64];
    int id = blockIdx.x;
    int xcd = id & 7, s = id >> 3;          // s in [0,128)
    int kh = s & 1;                         // k-half
    int s2 = s >> 1;                        // [0,64)
    int ytile = (s2 & 15) * 8 + xcd;        // 128 m-tiles, pinned to xcd
    int xtile = s2 >> 4;                    // 4 n-tiles
    int m0 = ytile * 64, n0 = xtile * 128;
    int kbase = kh * (K / 2);
    int tid = threadIdx.x;
    int w = tid >> 6, l = tid & 63;
    int wm = (w >> 1) * 32, wn = (w & 1) * 64;
    int lr = l & 15, lg = l >> 4;
    int lrow8 = l >> 3, lch = l & 7;
    int chg = lch ^ lrow8;

    f32x4 acc[2][4];
#pragma unroll
    for (int i = 0; i < 2; i++)
#pragma unroll
        for (int j = 0; j < 4; j++) acc[i][j] = (f32x4){0.f, 0.f, 0.f, 0.f};

#pragma unroll
    for (int j = 0; j < 2; j++) {
        int br = w * 16 + j * 8;
        GLOAD16(A + (long)(m0 + br + lrow8) * K + kbase + chg * 8, &Al[0][br * 64]);
    }
#pragma unroll
    for (int j = 0; j < 4; j++) {
        int br = w * 32 + j * 8;
        GLOAD16(Bt + (long)(n0 + br + lrow8) * K + kbase + chg * 8, &Bl[0][br * 64]);
    }

    int nk = (K / 2) / 64;
    for (int kt = 0; kt < nk; kt++) {
        int cur = kt & 1;
        __syncthreads();
        if (kt + 1 < nk) {
            int k0 = kbase + (kt + 1) * 64;
#pragma unroll
            for (int j = 0; j < 2; j++) {
                int br = w * 16 + j * 8;
                GLOAD16(A + (long)(m0 + br + lrow8) * K + k0 + chg * 8, &Al[cur ^ 1][br * 64]);
            }
#pragma unroll
            for (int j = 0; j < 4; j++) {
                int br = w * 32 + j * 8;
                GLOAD16(Bt + (long)(n0 + br + lrow8) * K + k0 + chg * 8, &Bl[cur ^ 1][br * 64]);
            }
        }
        const unsigned short* Ab = Al[cur];
        const unsigned short* Bb = Bl[cur];
#pragma unroll
        for (int kc = 0; kc < 2; kc++) {
            bf16x8 af[2], bff[4];
#pragma unroll
            for (int i = 0; i < 2; i++) {
                int row = wm + i * 16 + lr;
                int ch = (kc * 4 + lg) ^ (row & 7);
                af[i] = *(const bf16x8*)(Ab + row * 64 + ch * 8);
            }
#pragma unroll
            for (int j = 0; j < 4; j++) {
                int rowb = wn + j * 16 + lr;
                int chb = (kc * 4 + lg) ^ (rowb & 7);
                bff[j] = *(const bf16x8*)(Bb + rowb * 64 + chb * 8);
            }
#pragma unroll
            for (int i = 0; i < 2; i++)
#pragma unroll
                for (int j = 0; j < 4; j++)
                    acc[i][j] = __builtin_amdgcn_mfma_f32_16x16x32_bf16(af[i], bff[j], acc[i][j], 0, 0, 0);
        }
    }

#pragma unroll
    for (int i = 0; i < 2; i++)
#pragma unroll
        for (int j = 0; j < 4; j++) {
            int row = m0 + wm + i * 16 + lg * 4;
            int col = n0 + wn + j * 16 + lr;
#pragma unroll
            for (int r = 0; r < 4; r++)
                atomicAdd(&outf[(long)(row + r) * N + col], acc[i][j][r]);
        }
}

// ---------------- flash attention (causal), bf16 MFMA, v8 ----------------
// r5 structure + V-direct-from-L2, with the V loads PINNED early via
// sched_barrier(0) (r7 showed the compiler sinks them to the PV use point,
// exposing full L2 latency; the fence stops scheduler motion across it).
// V loads issue before the K-DMA prefetch: in-order vmcnt retirement means
// PV's wait leaves the K prefetch in flight. LDS 24KB (K dbuf + P).
// launch_bounds(256,4): VGPR cap 128 -> holds ~32 VGPR of vf live, no spill.
__global__ __launch_bounds__(256, 4) void k_attn(const unsigned short* __restrict__ qb,
                                                 const unsigned short* __restrict__ kb,
                                                 const unsigned short* __restrict__ vtb,
                                                 unsigned short* __restrict__ yb) {
    __shared__ unsigned short Kl[2][64 * 64];
    __shared__ unsigned short Pl[4 * 16 * 64];

    int id = blockIdx.x;
    int xcd = id & 7, s = id >> 3;          // s in [0,128)
    int bh = (s & 3) * 8 + xcd;             // 4 heads per XCD
    int qt = 31 - (s >> 2);                 // longest first
    int q0 = qt * 64;
    int nkt = qt + 1;

    int tid = threadIdx.x, w = tid >> 6, l = tid & 63;
    int lr = l & 15, lg = l >> 4;
    int lrow8 = l >> 3, lch = l & 7;
    int chg = lch ^ lrow8;  // inverse-swizzled global chunk for linear LDS dest
    long hbase = (long)bh * NT * NHD;
    const float QSCALE = 0.125f * 1.4426950408889634f;  // 1/sqrt(64) * log2(e)

    // Q fragments (B-operand), scaled
    int qrow = q0 + w * 16 + lr;
    bf16x8 qf[2];
#pragma unroll
    for (int dh = 0; dh < 2; dh++) {
        bf16x8 v = *(const bf16x8*)(qb + hbase + (long)qrow * NHD + dh * 32 + lg * 8);
#pragma unroll
        for (int e = 0; e < 8; e++) v[e] = (short)f2bf(bf2f((unsigned short)v[e]) * QSCALE);
        qf[dh] = v;
    }

    float mrun = -__builtin_inff(), ell = 0.f;
    f32x4 ot[4];
#pragma unroll
    for (int i = 0; i < 4; i++) ot[i] = (f32x4){0.f, 0.f, 0.f, 0.f};

    // stage K tile 0 -> buf 0 (wave w stages rows [w*16, w*16+16))
#pragma unroll
    for (int j = 0; j < 2; j++) {
        int br = w * 16 + j * 8;
        GLOAD16(kb + hbase + (long)(br + lrow8) * NHD + chg * 8, &Kl[0][br * 64]);
    }

    for (int kt = 0; kt < nkt; kt++) {
        int b = kt & 1;
        __syncthreads();  // drains vmcnt(0): K tile kt's DMA complete

        // V frags for CURRENT tile, direct from L2. Issued FIRST (oldest in
        // vmcnt order), then K prefetch, then a hard scheduler fence so the
        // compiler cannot sink these loads down to the PV use point.
        const unsigned short* Vg = vtb + hbase + kt * 64;
        bf16x8 vf[4][2];
#pragma unroll
        for (int md = 0; md < 4; md++)
#pragma unroll
            for (int th = 0; th < 2; th++)
                vf[md][th] = *(const bf16x8*)(Vg + (long)(md * 16 + lr) * NT + (th * 4 + lg) * 8);

        // prefetch K tile kt+1 (younger than V loads; stays in flight)
        if (kt + 1 < nkt) {
            int k0s = (kt + 1) * 64;
#pragma unroll
            for (int j = 0; j < 2; j++) {
                int br = w * 16 + j * 8;
                GLOAD16(kb + hbase + (long)(k0s + br + lrow8) * NHD + chg * 8,
                        &Kl[b ^ 1][br * 64]);
            }
        }
        __builtin_amdgcn_sched_barrier(0);  // pin all loads above this point

        int k0 = kt * 64;
        const unsigned short* Kb = Kl[b];

        // S^T = mfma(K, Q): rows t (4 subtiles of 16), col q = lr
        f32x4 st[4];
        __builtin_amdgcn_s_setprio(1);
#pragma unroll
        for (int sub = 0; sub < 4; sub++) {
            f32x4 z = (f32x4){0.f, 0.f, 0.f, 0.f};
#pragma unroll
            for (int dh = 0; dh < 2; dh++) {
                int row = sub * 16 + lr;
                int ch = (dh * 4 + lg) ^ (row & 7);
                bf16x8 kf = *(const bf16x8*)(Kb + row * 64 + ch * 8);
                z = __builtin_amdgcn_mfma_f32_16x16x32_bf16(kf, qf[dh], z, 0, 0, 0);
            }
            st[sub] = z;
        }
        __builtin_amdgcn_s_setprio(0);

        // causal mask: only the last k-tile can have t > q
        if (kt == nkt - 1) {
            int qg = q0 + w * 16 + lr;
#pragma unroll
            for (int sub = 0; sub < 4; sub++)
#pragma unroll
                for (int r = 0; r < 4; r++) {
                    int tg = k0 + sub * 16 + lg * 4 + r;
                    if (tg > qg) st[sub][r] = -__builtin_inff();
                }
        }

        // row(q) max: 16 in-lane + reduce across lg groups
        float pmax = st[0][0];
#pragma unroll
        for (int sub = 0; sub < 4; sub++)
#pragma unroll
            for (int r = 0; r < 4; r++) pmax = fmaxf(pmax, st[sub][r]);
        pmax = fmaxf(pmax, __shfl_xor(pmax, 16));
        pmax = fmaxf(pmax, __shfl_xor(pmax, 32));

        // defer-max: skip rescale while tile max growth <= 8 (log2 units)
        if (!__all(pmax - mrun <= 8.f)) {
            float mn = fmaxf(mrun, pmax);
            float alpha = exp2_fast(mrun - mn);
            ell *= alpha;
#pragma unroll
            for (int sub = 0; sub < 4; sub++) ot[sub] *= alpha;
            mrun = mn;
        }

        // P = exp2(S - m), pack to bf16, stash per-wave in LDS
        float psum = 0.f;
#pragma unroll
        for (int sub = 0; sub < 4; sub++) {
            float p0 = exp2_fast(st[sub][0] - mrun);
            float p1 = exp2_fast(st[sub][1] - mrun);
            float p2 = exp2_fast(st[sub][2] - mrun);
            float p3 = exp2_fast(st[sub][3] - mrun);
            psum += (p0 + p1) + (p2 + p3);
            u32x2 pw;
            pw[0] = cvt_pk_bf16(p0, p1);
            pw[1] = cvt_pk_bf16(p2, p3);
            int t = sub * 16 + lg * 4;
            int ch = t >> 3;
            *(u32x2*)(Pl + w * 1024 + lr * 64 + ((ch ^ (lr & 7)) * 8) + (t & 7)) = pw;
        }
        psum += __shfl_xor(psum, 16);
        psum += __shfl_xor(psum, 32);
        ell += psum;

        // PV: O^T[d][q] += V^T[d][t] * P^T[t][q]  (per-wave Pl; V from regs)
        bf16x8 pf[2];
#pragma unroll
        for (int th = 0; th < 2; th++) {
            int ch = (th * 4 + lg) ^ (lr & 7);
            pf[th] = *(const bf16x8*)(Pl + w * 1024 + lr * 64 + ch * 8);
        }
        __builtin_amdgcn_s_setprio(1);
#pragma unroll
        for (int md = 0; md < 4; md++)
#pragma unroll
            for (int th = 0; th < 2; th++)
                ot[md] = __builtin_amdgcn_mfma_f32_16x16x32_bf16(vf[md][th], pf[th], ot[md], 0, 0, 0);
        __builtin_amdgcn_s_setprio(0);
    }

    float inv = 1.f / ell;
    long yrow = (long)((bh >> 3) * NT + q0 + w * 16 + lr);
    int hcol = (bh & 7) * NHD;
#pragma unroll
    for (int sub = 0; sub < 4; sub++) {
        bf16x4 o;
#pragma unroll
        for (int r = 0; r < 4; r++) o[r] = (short)f2bf(ot[sub][r] * inv);
        *(bf16x4*)(yb + yrow * ND + hcol + sub * 16 + lg * 4) = o;
    }
}

extern "C" void kernel_launch(void* const* d_in, const int* in_sizes, int n_in,
                              void* d_out, int out_size, void* d_ws, size_t ws_size,
                              hipStream_t stream) {
    const float* x = (const float*)d_in[0];
    // d_in[1] = attn_mask (causal tril by construction; hardcoded)
    const float* Wqkv = (const float*)d_in[2];
    const float* Wout = (const float*)d_in[3];

    char* ws = (char*)d_ws;
    unsigned short* xb = (unsigned short*)(ws);                        // [8192][512]
    unsigned short* wqkvt = (unsigned short*)(ws + 8388608);           // [1536][512]
    unsigned short* woutt = (unsigned short*)(ws + 8388608 + 1572864); // [512][512]
    unsigned short* qbp = (unsigned short*)(ws + 10485760);            // [b,h,t,hd]
    unsigned short* kbp = (unsigned short*)(ws + 10485760 + 8388608);  // [b,h,t,hd]
    unsigned short* vtb = (unsigned short*)(ws + 10485760 + 16777216); // [b,h,hd,t]
    unsigned short* yb = xb;  // reuse x's slot after GEMM1
    float* out = (float*)d_out;

    // zero d_out for gemm2's split-K atomic accumulation (graph-capturable)
    hipMemsetAsync(out, 0, (size_t)NB * NT * ND * sizeof(float), stream);

    k_prep<<<dim3(3072), dim3(256), 0, stream>>>(x, Wqkv, Wout, xb, wqkvt, woutt);
    k_gemm1<<<dim3(768), dim3(256), 0, stream>>>(xb, wqkvt, qbp, kbp, vtb, ND, 3 * ND);
    k_attn<<<dim3(1024), dim3(256), 0, stream>>>(qbp, kbp, vtb, yb);
    k_gemm2<<<dim3(1024), dim3(256), 0, stream>>>(yb, woutt, out, ND, ND);
}

// Round 10
// 167.450 us; speedup vs baseline: 1.3077x; 1.3077x over previous
//
#include <hip/hip_runtime.h>

#define NB 4
#define NT 2048
#define ND 512
#define NH 8
#define NHD 64

typedef __attribute__((ext_vector_type(4))) float f32x4;
typedef __attribute__((ext_vector_type(8))) short bf16x8;
typedef __attribute__((ext_vector_type(4))) short bf16x4;
typedef __attribute__((ext_vector_type(4))) unsigned int u32x4;
typedef __attribute__((ext_vector_type(2))) unsigned int u32x2;

__device__ __forceinline__ unsigned short f2bf(float f) {
    unsigned u = __builtin_bit_cast(unsigned, f);
    u += 0x7FFFu + ((u >> 16) & 1u);
    return (unsigned short)(u >> 16);
}
__device__ __forceinline__ float bf2f(unsigned short h) {
    unsigned u = ((unsigned)h) << 16;
    return __builtin_bit_cast(float, u);
}
__device__ __forceinline__ float exp2_fast(float x) {
    float r;
    asm("v_exp_f32 %0, %1" : "=v"(r) : "v"(x));
    return r;
}
__device__ __forceinline__ unsigned cvt_pk_bf16(float lo, float hi) {
    unsigned r;
    asm("v_cvt_pk_bf16_f32 %0, %1, %2" : "=v"(r) : "v"(lo), "v"(hi));
    return r;
}

#define GLOAD16(g, s)                                                          \
    __builtin_amdgcn_global_load_lds(                                          \
        (const __attribute__((address_space(1))) unsigned int*)(g),            \
        (__attribute__((address_space(3))) unsigned int*)(s), 16, 0, 0)

// ---------------- fused prep: cvt(x) + tr(Wqkv) + tr(Wout) ----------------
__global__ __launch_bounds__(256) void k_prep(const float* __restrict__ x,
                                              const float* __restrict__ Wqkv,
                                              const float* __restrict__ Wout,
                                              unsigned short* __restrict__ xb,
                                              unsigned short* __restrict__ wqkvt,
                                              unsigned short* __restrict__ woutt) {
    __shared__ unsigned short tile[32][33];
    int id = blockIdx.x;
    if (id < 2048) {
        int i = id * 256 + threadIdx.x;
        const float* p = x + (long)i * 8;
        f32x4 a = *(const f32x4*)p;
        f32x4 b = *(const f32x4*)(p + 4);
        bf16x8 o;
#pragma unroll
        for (int e = 0; e < 4; e++) {
            o[e] = (short)f2bf(a[e]);
            o[e + 4] = (short)f2bf(b[e]);
        }
        *(bf16x8*)(xb + (long)i * 8) = o;
        return;
    }
    const float* in;
    unsigned short* out;
    int R, C, bx, by;
    if (id < 2816) {
        int t = id - 2048;
        in = Wqkv; out = wqkvt; R = 512; C = 1536;
        bx = t % 48; by = t / 48;
    } else {
        int t = id - 2816;
        in = Wout; out = woutt; R = 512; C = 512;
        bx = t % 16; by = t / 16;
    }
    int c0 = bx * 32, r0 = by * 32;
    int tx = threadIdx.x & 31, ty = threadIdx.x >> 5;
#pragma unroll
    for (int j = 0; j < 32; j += 8)
        tile[ty + j][tx] = f2bf(in[(long)(r0 + ty + j) * C + c0 + tx]);
    __syncthreads();
#pragma unroll
    for (int j = 0; j < 32; j += 8)
        out[(long)(c0 + ty + j) * R + r0 + tx] = tile[tx][ty + j];
}

// ---------------- bf16 GEMM1: qkv = xb * Wqkv^T, scatter epilogue ----------
__global__ __launch_bounds__(256) void k_gemm1(const unsigned short* __restrict__ A,
                                               const unsigned short* __restrict__ Bt,
                                               unsigned short* __restrict__ q,
                                               unsigned short* __restrict__ kk_,
                                               unsigned short* __restrict__ vt,
                                               int K, int N) {
    __shared__ unsigned short Al[128 * 64];
    __shared__ unsigned short Bl[128 * 64];
    int id = blockIdx.x;
    int xcd = id & 7, s = id >> 3;
    int ytile = (s & 7) * 8 + xcd;
    int xtile = s >> 3;
    int m0 = ytile * 128, n0 = xtile * 128;
    int tid = threadIdx.x;
    int w = tid >> 6, l = tid & 63;
    int wm = (w >> 1) * 64, wn = (w & 1) * 64;
    int lr = l & 15, lg = l >> 4;
    int lrow8 = l >> 3, lch = l & 7;
    int chg = lch ^ lrow8;

    f32x4 acc[4][4];
#pragma unroll
    for (int i = 0; i < 4; i++)
#pragma unroll
        for (int j = 0; j < 4; j++) acc[i][j] = (f32x4){0.f, 0.f, 0.f, 0.f};

    for (int k0 = 0; k0 < K; k0 += 64) {
        __syncthreads();
#pragma unroll
        for (int p = 0; p < 4; p++) {
            int br = p * 32 + w * 8;
            int row = br + lrow8;
            GLOAD16(A + (long)(m0 + row) * K + k0 + chg * 8, &Al[br * 64]);
            GLOAD16(Bt + (long)(n0 + row) * K + k0 + chg * 8, &Bl[br * 64]);
        }
        __syncthreads();
#pragma unroll
        for (int kc = 0; kc < 2; kc++) {
            bf16x8 af[4], bff[4];
#pragma unroll
            for (int i = 0; i < 4; i++) {
                int row = wm + i * 16 + lr;
                int ch = (kc * 4 + lg) ^ (row & 7);
                af[i] = *(const bf16x8*)(Al + row * 64 + ch * 8);
                int rowb = wn + i * 16 + lr;
                int chb = (kc * 4 + lg) ^ (rowb & 7);
                bff[i] = *(const bf16x8*)(Bl + rowb * 64 + chb * 8);
            }
#pragma unroll
            for (int i = 0; i < 4; i++)
#pragma unroll
                for (int j = 0; j < 4; j++)
                    acc[i][j] = __builtin_amdgcn_mfma_f32_16x16x32_bf16(af[i], bff[j], acc[i][j], 0, 0, 0);
        }
    }

#pragma unroll
    for (int i = 0; i < 4; i++)
#pragma unroll
        for (int j = 0; j < 4; j++) {
            int m = m0 + wm + i * 16 + lg * 4;
            int col = n0 + wn + j * 16 + lr;
            int sel = col >> 9;
            int cc = col & 511;
            int h = cc >> 6, hd = cc & 63;
            int b = m >> 11, t = m & 2047;
            long bh = (long)(b * NH + h);
            if (sel == 0) {
#pragma unroll
                for (int r = 0; r < 4; r++)
                    q[(bh * NT + t + r) * NHD + hd] = f2bf(acc[i][j][r]);
            } else if (sel == 1) {
#pragma unroll
                for (int r = 0; r < 4; r++)
                    kk_[(bh * NT + t + r) * NHD + hd] = f2bf(acc[i][j][r]);
            } else {
                bf16x4 pk;
#pragma unroll
                for (int r = 0; r < 4; r++) pk[r] = (short)f2bf(acc[i][j][r]);
                *(bf16x4*)(vt + (bh * NHD + hd) * NT + t) = pk;
            }
        }
}

// ---------------- bf16 GEMM2: out = yb * Wout^T (fp32 out) ----------------
__global__ __launch_bounds__(256) void k_gemm2(const unsigned short* __restrict__ A,
                                               const unsigned short* __restrict__ Bt,
                                               float* __restrict__ outf,
                                               int K, int N) {
    __shared__ unsigned short Al[2][64 * 64];
    __shared__ unsigned short Bl[2][128 * 64];
    int id = blockIdx.x;
    int xcd = id & 7, s = id >> 3;
    int ytile = (s & 15) * 8 + xcd;
    int xtile = s >> 4;
    int m0 = ytile * 64, n0 = xtile * 128;
    int tid = threadIdx.x;
    int w = tid >> 6, l = tid & 63;
    int wm = (w >> 1) * 32, wn = (w & 1) * 64;
    int lr = l & 15, lg = l >> 4;
    int lrow8 = l >> 3, lch = l & 7;
    int chg = lch ^ lrow8;

    f32x4 acc[2][4];
#pragma unroll
    for (int i = 0; i < 2; i++)
#pragma unroll
        for (int j = 0; j < 4; j++) acc[i][j] = (f32x4){0.f, 0.f, 0.f, 0.f};

#pragma unroll
    for (int j = 0; j < 2; j++) {
        int br = w * 16 + j * 8;
        GLOAD16(A + (long)(m0 + br + lrow8) * K + chg * 8, &Al[0][br * 64]);
    }
#pragma unroll
    for (int j = 0; j < 4; j++) {
        int br = w * 32 + j * 8;
        GLOAD16(Bt + (long)(n0 + br + lrow8) * K + chg * 8, &Bl[0][br * 64]);
    }

    int nk = K / 64;
    for (int kt = 0; kt < nk; kt++) {
        int cur = kt & 1;
        __syncthreads();
        if (kt + 1 < nk) {
            int k0 = (kt + 1) * 64;
#pragma unroll
            for (int j = 0; j < 2; j++) {
                int br = w * 16 + j * 8;
                GLOAD16(A + (long)(m0 + br + lrow8) * K + k0 + chg * 8, &Al[cur ^ 1][br * 64]);
            }
#pragma unroll
            for (int j = 0; j < 4; j++) {
                int br = w * 32 + j * 8;
                GLOAD16(Bt + (long)(n0 + br + lrow8) * K + k0 + chg * 8, &Bl[cur ^ 1][br * 64]);
            }
        }
        const unsigned short* Ab = Al[cur];
        const unsigned short* Bb = Bl[cur];
#pragma unroll
        for (int kc = 0; kc < 2; kc++) {
            bf16x8 af[2], bff[4];
#pragma unroll
            for (int i = 0; i < 2; i++) {
                int row = wm + i * 16 + lr;
                int ch = (kc * 4 + lg) ^ (row & 7);
                af[i] = *(const bf16x8*)(Ab + row * 64 + ch * 8);
            }
#pragma unroll
            for (int j = 0; j < 4; j++) {
                int rowb = wn + j * 16 + lr;
                int chb = (kc * 4 + lg) ^ (rowb & 7);
                bff[j] = *(const bf16x8*)(Bb + rowb * 64 + chb * 8);
            }
#pragma unroll
            for (int i = 0; i < 2; i++)
#pragma unroll
                for (int j = 0; j < 4; j++)
                    acc[i][j] = __builtin_amdgcn_mfma_f32_16x16x32_bf16(af[i], bff[j], acc[i][j], 0, 0, 0);
        }
    }

#pragma unroll
    for (int i = 0; i < 2; i++)
#pragma unroll
        for (int j = 0; j < 4; j++) {
            int row = m0 + wm + i * 16 + lg * 4;
            int col = n0 + wn + j * 16 + lr;
#pragma unroll
            for (int r = 0; r < 4; r++) outf[(long)(row + r) * N + col] = acc[i][j][r];
        }
}

// ---------------- flash attention (causal), bf16 MFMA, v9 ----------------
// r5 structure with KVBLK=32: LDS 40KB -> 20KB (K dbuf 8K + V dbuf 8K + P 4K)
// -> 8 blocks/CU (was 4) in a latency-bound kernel. Per-tile work halves,
// tile count doubles; fixed latencies amortize worse per tile but 2x TLP
// wins. Causal mask now needed on the last TWO 32-wide k-tiles. V rows are
// 64B (4 chunks): swizzle ^(row&3); P rows 64B likewise (^(lr&3)).
// launch_bounds (256,4): no forced VGPR cap (r6 lesson) — occupancy comes
// from actual VGPR (~50 <= 64 -> 8 waves/SIMD reachable).
__global__ __launch_bounds__(256, 4) void k_attn(const unsigned short* __restrict__ qb,
                                                 const unsigned short* __restrict__ kb,
                                                 const unsigned short* __restrict__ vtb,
                                                 unsigned short* __restrict__ yb) {
    __shared__ unsigned short Kl[2][32 * 64];  // [t 32][d 64], 128B rows
    __shared__ unsigned short Vl[2][64 * 32];  // [d 64][t 32], 64B rows
    __shared__ unsigned short Pl[4 * 16 * 32]; // per wave [q 16][t 32], 64B rows

    int id = blockIdx.x;
    int xcd = id & 7, s = id >> 3;          // s in [0,128)
    int bh = (s & 3) * 8 + xcd;             // 4 heads per XCD
    int qt = 31 - (s >> 2);                 // longest first
    int q0 = qt * 64;
    int nkt = 2 * qt + 2;                   // 32-wide k-tiles

    int tid = threadIdx.x, w = tid >> 6, l = tid & 63;
    int lr = l & 15, lg = l >> 4;
    int lrow8 = l >> 3, lch = l & 7;
    int chg = lch ^ lrow8;                  // K source chunk (8x16B rows)
    int vrow = l >> 2, vch = (l & 3) ^ ((l >> 2) & 3);  // V source chunk (4x16B rows)
    long hbase = (long)bh * NT * NHD;
    const float QSCALE = 0.125f * 1.4426950408889634f;  // 1/sqrt(64) * log2(e)

    // Q fragments (B-operand), scaled
    int qrow = q0 + w * 16 + lr;
    bf16x8 qf[2];
#pragma unroll
    for (int dh = 0; dh < 2; dh++) {
        bf16x8 v = *(const bf16x8*)(qb + hbase + (long)qrow * NHD + dh * 32 + lg * 8);
#pragma unroll
        for (int e = 0; e < 8; e++) v[e] = (short)f2bf(bf2f((unsigned short)v[e]) * QSCALE);
        qf[dh] = v;
    }

    float mrun = -__builtin_inff(), ell = 0.f;
    f32x4 ot[4];
#pragma unroll
    for (int i = 0; i < 4; i++) ot[i] = (f32x4){0.f, 0.f, 0.f, 0.f};

    // stage tile 0 -> buf 0: wave w stages K rows [w*8,w*8+8), V rows [w*16,w*16+16)
    GLOAD16(kb + hbase + (long)(w * 8 + lrow8) * NHD + chg * 8, &Kl[0][(w * 8) * 64]);
    GLOAD16(vtb + hbase + (long)(w * 16 + vrow) * NT + vch * 8, &Vl[0][(w * 16) * 32]);

    for (int kt = 0; kt < nkt; kt++) {
        int b = kt & 1;
        __syncthreads();  // drains vmcnt(0): tile kt's DMA complete, rendezvous
        if (kt + 1 < nkt) {
            int k0s = (kt + 1) * 32;
            GLOAD16(kb + hbase + (long)(k0s + w * 8 + lrow8) * NHD + chg * 8,
                    &Kl[b ^ 1][(w * 8) * 64]);
            GLOAD16(vtb + hbase + (long)(w * 16 + vrow) * NT + k0s + vch * 8,
                    &Vl[b ^ 1][(w * 16) * 32]);
        }
        int k0 = kt * 32;
        const unsigned short* Kb = Kl[b];
        const unsigned short* Vb = Vl[b];

        // S^T = mfma(K, Q): 2 subtiles of 16 t-rows, col q = lr
        f32x4 st[2];
        __builtin_amdgcn_s_setprio(1);
#pragma unroll
        for (int sub = 0; sub < 2; sub++) {
            f32x4 z = (f32x4){0.f, 0.f, 0.f, 0.f};
#pragma unroll
            for (int dh = 0; dh < 2; dh++) {
                int row = sub * 16 + lr;
                int ch = (dh * 4 + lg) ^ (row & 7);
                bf16x8 kf = *(const bf16x8*)(Kb + row * 64 + ch * 8);
                z = __builtin_amdgcn_mfma_f32_16x16x32_bf16(kf, qf[dh], z, 0, 0, 0);
            }
            st[sub] = z;
        }
        __builtin_amdgcn_s_setprio(0);

        // causal mask: the last TWO k-tiles cross the diagonal
        if (kt >= nkt - 2) {
            int qg = q0 + w * 16 + lr;
#pragma unroll
            for (int sub = 0; sub < 2; sub++)
#pragma unroll
                for (int r = 0; r < 4; r++) {
                    int tg = k0 + sub * 16 + lg * 4 + r;
                    if (tg > qg) st[sub][r] = -__builtin_inff();
                }
        }

        // row(q) max: 8 in-lane + reduce across lg groups
        float pmax = st[0][0];
#pragma unroll
        for (int sub = 0; sub < 2; sub++)
#pragma unroll
            for (int r = 0; r < 4; r++) pmax = fmaxf(pmax, st[sub][r]);
        pmax = fmaxf(pmax, __shfl_xor(pmax, 16));
        pmax = fmaxf(pmax, __shfl_xor(pmax, 32));

        // defer-max: skip rescale while tile max growth <= 8 (log2 units)
        if (!__all(pmax - mrun <= 8.f)) {
            float mn = fmaxf(mrun, pmax);
            float alpha = exp2_fast(mrun - mn);
            ell *= alpha;
#pragma unroll
            for (int sub = 0; sub < 4; sub++) ot[sub] *= alpha;
            mrun = mn;
        }

        // P = exp2(S - m), pack to bf16, stash per-wave in LDS ([16q][32t])
        unsigned short* Ps = Pl + w * 512 + lr * 32;
        float psum = 0.f;
#pragma unroll
        for (int sub = 0; sub < 2; sub++) {
            float p0 = exp2_fast(st[sub][0] - mrun);
            float p1 = exp2_fast(st[sub][1] - mrun);
            float p2 = exp2_fast(st[sub][2] - mrun);
            float p3 = exp2_fast(st[sub][3] - mrun);
            psum += (p0 + p1) + (p2 + p3);
            u32x2 pw;
            pw[0] = cvt_pk_bf16(p0, p1);
            pw[1] = cvt_pk_bf16(p2, p3);
            // t = sub*16 + lg*4 -> logical chunk = sub*2 + (lg>>1), 8B half (lg&1)
            *(u32x2*)(Ps + (((sub * 2 + (lg >> 1)) ^ (lr & 3)) * 8) + (lg & 1) * 4) = pw;
        }
        psum += __shfl_xor(psum, 16);
        psum += __shfl_xor(psum, 32);
        ell += psum;

        // PV: O^T[d][q] += V^T[d][t] * P^T[t][q]  (per-wave Pl, no barrier)
        bf16x8 pf = *(const bf16x8*)(Pl + w * 512 + lr * 32 + ((lg ^ (lr & 3)) * 8));
        __builtin_amdgcn_s_setprio(1);
#pragma unroll
        for (int md = 0; md < 4; md++) {
            int row = md * 16 + lr;
            int ch = lg ^ (row & 3);
            bf16x8 vf = *(const bf16x8*)(Vb + row * 32 + ch * 8);
            ot[md] = __builtin_amdgcn_mfma_f32_16x16x32_bf16(vf, pf, ot[md], 0, 0, 0);
        }
        __builtin_amdgcn_s_setprio(0);
    }

    float inv = 1.f / ell;
    long yrow = (long)((bh >> 3) * NT + q0 + w * 16 + lr);
    int hcol = (bh & 7) * NHD;
#pragma unroll
    for (int sub = 0; sub < 4; sub++) {
        bf16x4 o;
#pragma unroll
        for (int r = 0; r < 4; r++) o[r] = (short)f2bf(ot[sub][r] * inv);
        *(bf16x4*)(yb + yrow * ND + hcol + sub * 16 + lg * 4) = o;
    }
}

extern "C" void kernel_launch(void* const* d_in, const int* in_sizes, int n_in,
                              void* d_out, int out_size, void* d_ws, size_t ws_size,
                              hipStream_t stream) {
    const float* x = (const float*)d_in[0];
    // d_in[1] = attn_mask (causal tril by construction; hardcoded)
    const float* Wqkv = (const float*)d_in[2];
    const float* Wout = (const float*)d_in[3];

    char* ws = (char*)d_ws;
    unsigned short* xb = (unsigned short*)(ws);                        // [8192][512]
    unsigned short* wqkvt = (unsigned short*)(ws + 8388608);           // [1536][512]
    unsigned short* woutt = (unsigned short*)(ws + 8388608 + 1572864); // [512][512]
    unsigned short* qbp = (unsigned short*)(ws + 10485760);            // [b,h,t,hd]
    unsigned short* kbp = (unsigned short*)(ws + 10485760 + 8388608);  // [b,h,t,hd]
    unsigned short* vtb = (unsigned short*)(ws + 10485760 + 16777216); // [b,h,hd,t]
    unsigned short* yb = xb;  // reuse x's slot after GEMM1
    float* out = (float*)d_out;

    k_prep<<<dim3(3072), dim3(256), 0, stream>>>(x, Wqkv, Wout, xb, wqkvt, woutt);
    k_gemm1<<<dim3(768), dim3(256), 0, stream>>>(xb, wqkvt, qbp, kbp, vtb, ND, 3 * ND);
    k_attn<<<dim3(1024), dim3(256), 0, stream>>>(qbp, kbp, vtb, yb);
    k_gemm2<<<dim3(512), dim3(256), 0, stream>>>(yb, woutt, out, ND, ND);
}

// Round 11
// 154.629 us; speedup vs baseline: 1.4162x; 1.0829x over previous
//
#include <hip/hip_runtime.h>

#define NB 4
#define NT 2048
#define ND 512
#define NH 8
#define NHD 64

typedef __attribute__((ext_vector_type(4))) float f32x4;
typedef __attribute__((ext_vector_type(8))) short bf16x8;
typedef __attribute__((ext_vector_type(4))) short bf16x4;
typedef __attribute__((ext_vector_type(4))) unsigned int u32x4;
typedef __attribute__((ext_vector_type(2))) unsigned int u32x2;

__device__ __forceinline__ unsigned short f2bf(float f) {
    unsigned u = __builtin_bit_cast(unsigned, f);
    u += 0x7FFFu + ((u >> 16) & 1u);
    return (unsigned short)(u >> 16);
}
__device__ __forceinline__ float bf2f(unsigned short h) {
    unsigned u = ((unsigned)h) << 16;
    return __builtin_bit_cast(float, u);
}
__device__ __forceinline__ float exp2_fast(float x) {
    float r;
    asm("v_exp_f32 %0, %1" : "=v"(r) : "v"(x));
    return r;
}
__device__ __forceinline__ unsigned cvt_pk_bf16(float lo, float hi) {
    unsigned r;
    asm("v_cvt_pk_bf16_f32 %0, %1, %2" : "=v"(r) : "v"(lo), "v"(hi));
    return r;
}

#define GLOAD16(g, s)                                                          \
    __builtin_amdgcn_global_load_lds(                                          \
        (const __attribute__((address_space(1))) unsigned int*)(g),            \
        (__attribute__((address_space(3))) unsigned int*)(s), 16, 0, 0)

// ---------------- fused prep: cvt(x) + tr(Wqkv) + tr(Wout) ----------------
__global__ __launch_bounds__(256) void k_prep(const float* __restrict__ x,
                                              const float* __restrict__ Wqkv,
                                              const float* __restrict__ Wout,
                                              unsigned short* __restrict__ xb,
                                              unsigned short* __restrict__ wqkvt,
                                              unsigned short* __restrict__ woutt) {
    __shared__ unsigned short tile[32][33];
    int id = blockIdx.x;
    if (id < 2048) {
        int i = id * 256 + threadIdx.x;
        const float* p = x + (long)i * 8;
        f32x4 a = *(const f32x4*)p;
        f32x4 b = *(const f32x4*)(p + 4);
        bf16x8 o;
#pragma unroll
        for (int e = 0; e < 4; e++) {
            o[e] = (short)f2bf(a[e]);
            o[e + 4] = (short)f2bf(b[e]);
        }
        *(bf16x8*)(xb + (long)i * 8) = o;
        return;
    }
    const float* in;
    unsigned short* out;
    int R, C, bx, by;
    if (id < 2816) {
        int t = id - 2048;
        in = Wqkv; out = wqkvt; R = 512; C = 1536;
        bx = t % 48; by = t / 48;
    } else {
        int t = id - 2816;
        in = Wout; out = woutt; R = 512; C = 512;
        bx = t % 16; by = t / 16;
    }
    int c0 = bx * 32, r0 = by * 32;
    int tx = threadIdx.x & 31, ty = threadIdx.x >> 5;
#pragma unroll
    for (int j = 0; j < 32; j += 8)
        tile[ty + j][tx] = f2bf(in[(long)(r0 + ty + j) * C + c0 + tx]);
    __syncthreads();
#pragma unroll
    for (int j = 0; j < 32; j += 8)
        out[(long)(c0 + ty + j) * R + r0 + tx] = tile[tx][ty + j];
}

// ---------------- bf16 GEMM1: qkv = xb * Wqkv^T, scatter epilogue ----------
// m97-structure loop. q/k output blocks (n0<1024) use SWAPPED-operand MFMA
// (C^T: rows=n): the 4 acc values per fragment become consecutive hd ->
// one bf16x4 coalesced store each (16 stores/thread, was 64x 2B scatter).
// v blocks keep original orientation (bf16x4 into [hd][t], already good).
__global__ __launch_bounds__(256) void k_gemm1(const unsigned short* __restrict__ A,
                                               const unsigned short* __restrict__ Bt,
                                               unsigned short* __restrict__ q,
                                               unsigned short* __restrict__ kk_,
                                               unsigned short* __restrict__ vt,
                                               int K, int N) {
    __shared__ unsigned short Al[128 * 64];
    __shared__ unsigned short Bl[128 * 64];
    int id = blockIdx.x;
    int xcd = id & 7, s = id >> 3;
    int ytile = (s & 7) * 8 + xcd;
    int xtile = s >> 3;
    int m0 = ytile * 128, n0 = xtile * 128;
    bool swp = (xtile < 8);  // q/k blocks -> swapped MFMA (C^T)
    int tid = threadIdx.x;
    int w = tid >> 6, l = tid & 63;
    int wm = (w >> 1) * 64, wn = (w & 1) * 64;
    int lr = l & 15, lg = l >> 4;
    int lrow8 = l >> 3, lch = l & 7;
    int chg = lch ^ lrow8;

    f32x4 acc[4][4];
#pragma unroll
    for (int i = 0; i < 4; i++)
#pragma unroll
        for (int j = 0; j < 4; j++) acc[i][j] = (f32x4){0.f, 0.f, 0.f, 0.f};

    for (int k0 = 0; k0 < K; k0 += 64) {
        __syncthreads();
#pragma unroll
        for (int p = 0; p < 4; p++) {
            int br = p * 32 + w * 8;
            int row = br + lrow8;
            GLOAD16(A + (long)(m0 + row) * K + k0 + chg * 8, &Al[br * 64]);
            GLOAD16(Bt + (long)(n0 + row) * K + k0 + chg * 8, &Bl[br * 64]);
        }
        __syncthreads();
#pragma unroll
        for (int kc = 0; kc < 2; kc++) {
            bf16x8 af[4], bff[4];
#pragma unroll
            for (int i = 0; i < 4; i++) {
                int row = wm + i * 16 + lr;
                int ch = (kc * 4 + lg) ^ (row & 7);
                af[i] = *(const bf16x8*)(Al + row * 64 + ch * 8);
                int rowb = wn + i * 16 + lr;
                int chb = (kc * 4 + lg) ^ (rowb & 7);
                bff[i] = *(const bf16x8*)(Bl + rowb * 64 + chb * 8);
            }
            if (swp) {
#pragma unroll
                for (int i = 0; i < 4; i++)
#pragma unroll
                    for (int j = 0; j < 4; j++)
                        acc[i][j] = __builtin_amdgcn_mfma_f32_16x16x32_bf16(bff[j], af[i], acc[i][j], 0, 0, 0);
            } else {
#pragma unroll
                for (int i = 0; i < 4; i++)
#pragma unroll
                    for (int j = 0; j < 4; j++)
                        acc[i][j] = __builtin_amdgcn_mfma_f32_16x16x32_bf16(af[i], bff[j], acc[i][j], 0, 0, 0);
            }
        }
    }

    if (swp) {
        // C^T: row n = n0+wn+j*16+lg*4+r (consecutive hd in r), col m = m0+wm+i*16+lr
#pragma unroll
        for (int i = 0; i < 4; i++)
#pragma unroll
            for (int j = 0; j < 4; j++) {
                int nb = n0 + wn + j * 16 + lg * 4;  // hd-consecutive base
                int m = m0 + wm + i * 16 + lr;
                int sel = nb >> 9;
                int cc = nb & 511;
                int h = cc >> 6, hdb = cc & 63;
                int b = m >> 11, t = m & 2047;
                long bh = (long)(b * NH + h);
                unsigned short* dst = (sel == 0) ? q : kk_;
                bf16x4 pk;
#pragma unroll
                for (int r = 0; r < 4; r++) pk[r] = (short)f2bf(acc[i][j][r]);
                *(bf16x4*)(dst + (bh * NT + t) * NHD + hdb) = pk;
            }
    } else {
        // original: row m = m0+wm+i*16+lg*4+r (consecutive t in r), col n (hd fixed)
#pragma unroll
        for (int i = 0; i < 4; i++)
#pragma unroll
            for (int j = 0; j < 4; j++) {
                int m = m0 + wm + i * 16 + lg * 4;
                int col = n0 + wn + j * 16 + lr;
                int cc = col & 511;
                int h = cc >> 6, hd = cc & 63;
                int b = m >> 11, t = m & 2047;
                long bh = (long)(b * NH + h);
                bf16x4 pk;
#pragma unroll
                for (int r = 0; r < 4; r++) pk[r] = (short)f2bf(acc[i][j][r]);
                *(bf16x4*)(vt + (bh * NHD + hd) * NT + t) = pk;
            }
    }
}

// ---------------- bf16 GEMM2: out = yb * Wout^T (fp32 out) ----------------
__global__ __launch_bounds__(256) void k_gemm2(const unsigned short* __restrict__ A,
                                               const unsigned short* __restrict__ Bt,
                                               float* __restrict__ outf,
                                               int K, int N) {
    __shared__ unsigned short Al[2][64 * 64];
    __shared__ unsigned short Bl[2][128 * 64];
    int id = blockIdx.x;
    int xcd = id & 7, s = id >> 3;
    int ytile = (s & 15) * 8 + xcd;
    int xtile = s >> 4;
    int m0 = ytile * 64, n0 = xtile * 128;
    int tid = threadIdx.x;
    int w = tid >> 6, l = tid & 63;
    int wm = (w >> 1) * 32, wn = (w & 1) * 64;
    int lr = l & 15, lg = l >> 4;
    int lrow8 = l >> 3, lch = l & 7;
    int chg = lch ^ lrow8;

    f32x4 acc[2][4];
#pragma unroll
    for (int i = 0; i < 2; i++)
#pragma unroll
        for (int j = 0; j < 4; j++) acc[i][j] = (f32x4){0.f, 0.f, 0.f, 0.f};

#pragma unroll
    for (int j = 0; j < 2; j++) {
        int br = w * 16 + j * 8;
        GLOAD16(A + (long)(m0 + br + lrow8) * K + chg * 8, &Al[0][br * 64]);
    }
#pragma unroll
    for (int j = 0; j < 4; j++) {
        int br = w * 32 + j * 8;
        GLOAD16(Bt + (long)(n0 + br + lrow8) * K + chg * 8, &Bl[0][br * 64]);
    }

    int nk = K / 64;
    for (int kt = 0; kt < nk; kt++) {
        int cur = kt & 1;
        __syncthreads();
        if (kt + 1 < nk) {
            int k0 = (kt + 1) * 64;
#pragma unroll
            for (int j = 0; j < 2; j++) {
                int br = w * 16 + j * 8;
                GLOAD16(A + (long)(m0 + br + lrow8) * K + k0 + chg * 8, &Al[cur ^ 1][br * 64]);
            }
#pragma unroll
            for (int j = 0; j < 4; j++) {
                int br = w * 32 + j * 8;
                GLOAD16(Bt + (long)(n0 + br + lrow8) * K + k0 + chg * 8, &Bl[cur ^ 1][br * 64]);
            }
        }
        const unsigned short* Ab = Al[cur];
        const unsigned short* Bb = Bl[cur];
#pragma unroll
        for (int kc = 0; kc < 2; kc++) {
            bf16x8 af[2], bff[4];
#pragma unroll
            for (int i = 0; i < 2; i++) {
                int row = wm + i * 16 + lr;
                int ch = (kc * 4 + lg) ^ (row & 7);
                af[i] = *(const bf16x8*)(Ab + row * 64 + ch * 8);
            }
#pragma unroll
            for (int j = 0; j < 4; j++) {
                int rowb = wn + j * 16 + lr;
                int chb = (kc * 4 + lg) ^ (rowb & 7);
                bff[j] = *(const bf16x8*)(Bb + rowb * 64 + chb * 8);
            }
#pragma unroll
            for (int i = 0; i < 2; i++)
#pragma unroll
                for (int j = 0; j < 4; j++)
                    acc[i][j] = __builtin_amdgcn_mfma_f32_16x16x32_bf16(af[i], bff[j], acc[i][j], 0, 0, 0);
        }
    }

#pragma unroll
    for (int i = 0; i < 2; i++)
#pragma unroll
        for (int j = 0; j < 4; j++) {
            int row = m0 + wm + i * 16 + lg * 4;
            int col = n0 + wn + j * 16 + lr;
#pragma unroll
            for (int r = 0; r < 4; r++) outf[(long)(row + r) * N + col] = acc[i][j][r];
        }
}

// ---------------- flash attention (causal), bf16 MFMA, r5-exact -----------
// QBLK=64 (4 waves x 16 q-rows), KVBLK=64, grid 1024, XCD-pinned heads,
// longest-first, GLOAD16 dbuf staging, 1 barrier/tile, diagonal-only mask,
// exp2 softmax, defer-max, cvt_pk packing, setprio. Proven 47.6 us.
__global__ __launch_bounds__(256, 4) void k_attn(const unsigned short* __restrict__ qb,
                                                 const unsigned short* __restrict__ kb,
                                                 const unsigned short* __restrict__ vtb,
                                                 unsigned short* __restrict__ yb) {
    __shared__ unsigned short Kl[2][64 * 64];
    __shared__ unsigned short Vl[2][64 * 64];  // V^T tile: rows d(64), cols t(64)
    __shared__ unsigned short Pl[4 * 16 * 64];

    int id = blockIdx.x;
    int xcd = id & 7, s = id >> 3;          // s in [0,128)
    int bh = (s & 3) * 8 + xcd;             // 4 heads per XCD
    int qt = 31 - (s >> 2);                 // longest first
    int q0 = qt * 64;
    int nkt = qt + 1;

    int tid = threadIdx.x, w = tid >> 6, l = tid & 63;
    int lr = l & 15, lg = l >> 4;
    int lrow8 = l >> 3, lch = l & 7;
    int chg = lch ^ lrow8;  // inverse-swizzled global chunk for linear LDS dest
    long hbase = (long)bh * NT * NHD;
    const float QSCALE = 0.125f * 1.4426950408889634f;  // 1/sqrt(64) * log2(e)

    // Q fragments (B-operand), scaled
    int qrow = q0 + w * 16 + lr;
    bf16x8 qf[2];
#pragma unroll
    for (int dh = 0; dh < 2; dh++) {
        bf16x8 v = *(const bf16x8*)(qb + hbase + (long)qrow * NHD + dh * 32 + lg * 8);
#pragma unroll
        for (int e = 0; e < 8; e++) v[e] = (short)f2bf(bf2f((unsigned short)v[e]) * QSCALE);
        qf[dh] = v;
    }

    float mrun = -__builtin_inff(), ell = 0.f;
    f32x4 ot[4];
#pragma unroll
    for (int i = 0; i < 4; i++) ot[i] = (f32x4){0.f, 0.f, 0.f, 0.f};

    // stage tile 0 -> buf 0 (wave w stages rows [w*16, w*16+16) of K and V^T)
    {
#pragma unroll
        for (int j = 0; j < 2; j++) {
            int br = w * 16 + j * 8;
            GLOAD16(kb + hbase + (long)(br + lrow8) * NHD + chg * 8, &Kl[0][br * 64]);
            GLOAD16(vtb + hbase + (long)(br + lrow8) * NT + chg * 8, &Vl[0][br * 64]);
        }
    }

    for (int kt = 0; kt < nkt; kt++) {
        int b = kt & 1;
        __syncthreads();  // drains vmcnt(0): tile kt's DMA complete, rendezvous
        if (kt + 1 < nkt) {
            int k0s = (kt + 1) * 64;
#pragma unroll
            for (int j = 0; j < 2; j++) {
                int br = w * 16 + j * 8;
                GLOAD16(kb + hbase + (long)(k0s + br + lrow8) * NHD + chg * 8,
                        &Kl[b ^ 1][br * 64]);
                GLOAD16(vtb + hbase + (long)(br + lrow8) * NT + k0s + chg * 8,
                        &Vl[b ^ 1][br * 64]);
            }
        }
        int k0 = kt * 64;
        const unsigned short* Kb = Kl[b];
        const unsigned short* Vb = Vl[b];

        // S^T = mfma(K, Q): rows t (4 subtiles of 16), col q = lr
        f32x4 st[4];
        __builtin_amdgcn_s_setprio(1);
#pragma unroll
        for (int sub = 0; sub < 4; sub++) {
            f32x4 z = (f32x4){0.f, 0.f, 0.f, 0.f};
#pragma unroll
            for (int dh = 0; dh < 2; dh++) {
                int row = sub * 16 + lr;
                int ch = (dh * 4 + lg) ^ (row & 7);
                bf16x8 kf = *(const bf16x8*)(Kb + row * 64 + ch * 8);
                z = __builtin_amdgcn_mfma_f32_16x16x32_bf16(kf, qf[dh], z, 0, 0, 0);
            }
            st[sub] = z;
        }
        __builtin_amdgcn_s_setprio(0);

        // causal mask: only the last k-tile can have t > q
        if (kt == nkt - 1) {
            int qg = q0 + w * 16 + lr;
#pragma unroll
            for (int sub = 0; sub < 4; sub++)
#pragma unroll
                for (int r = 0; r < 4; r++) {
                    int tg = k0 + sub * 16 + lg * 4 + r;
                    if (tg > qg) st[sub][r] = -__builtin_inff();
                }
        }

        // row(q) max: 16 in-lane + reduce across lg groups
        float pmax = st[0][0];
#pragma unroll
        for (int sub = 0; sub < 4; sub++)
#pragma unroll
            for (int r = 0; r < 4; r++) pmax = fmaxf(pmax, st[sub][r]);
        pmax = fmaxf(pmax, __shfl_xor(pmax, 16));
        pmax = fmaxf(pmax, __shfl_xor(pmax, 32));

        // defer-max: skip rescale while tile max growth <= 8 (log2 units)
        if (!__all(pmax - mrun <= 8.f)) {
            float mn = fmaxf(mrun, pmax);
            float alpha = exp2_fast(mrun - mn);
            ell *= alpha;
#pragma unroll
            for (int sub = 0; sub < 4; sub++) ot[sub] *= alpha;
            mrun = mn;
        }

        // P = exp2(S - m), pack to bf16, stash per-wave in LDS
        float psum = 0.f;
#pragma unroll
        for (int sub = 0; sub < 4; sub++) {
            float p0 = exp2_fast(st[sub][0] - mrun);
            float p1 = exp2_fast(st[sub][1] - mrun);
            float p2 = exp2_fast(st[sub][2] - mrun);
            float p3 = exp2_fast(st[sub][3] - mrun);
            psum += (p0 + p1) + (p2 + p3);
            u32x2 pw;
            pw[0] = cvt_pk_bf16(p0, p1);
            pw[1] = cvt_pk_bf16(p2, p3);
            int t = sub * 16 + lg * 4;
            int ch = t >> 3;
            *(u32x2*)(Pl + w * 1024 + lr * 64 + ((ch ^ (lr & 7)) * 8) + (t & 7)) = pw;
        }
        psum += __shfl_xor(psum, 16);
        psum += __shfl_xor(psum, 32);
        ell += psum;

        // PV: O^T[d][q] += V^T[d][t] * P^T[t][q]  (per-wave Pl, no barrier)
        bf16x8 pf[2];
#pragma unroll
        for (int th = 0; th < 2; th++) {
            int ch = (th * 4 + lg) ^ (lr & 7);
            pf[th] = *(const bf16x8*)(Pl + w * 1024 + lr * 64 + ch * 8);
        }
        __builtin_amdgcn_s_setprio(1);
#pragma unroll
        for (int md = 0; md < 4; md++) {
#pragma unroll
            for (int th = 0; th < 2; th++) {
                int row = md * 16 + lr;
                int ch = (th * 4 + lg) ^ (row & 7);
                bf16x8 vf = *(const bf16x8*)(Vb + row * 64 + ch * 8);
                ot[md] = __builtin_amdgcn_mfma_f32_16x16x32_bf16(vf, pf[th], ot[md], 0, 0, 0);
            }
        }
        __builtin_amdgcn_s_setprio(0);
    }

    float inv = 1.f / ell;
    long yrow = (long)((bh >> 3) * NT + q0 + w * 16 + lr);
    int hcol = (bh & 7) * NHD;
#pragma unroll
    for (int sub = 0; sub < 4; sub++) {
        bf16x4 o;
#pragma unroll
        for (int r = 0; r < 4; r++) o[r] = (short)f2bf(ot[sub][r] * inv);
        *(bf16x4*)(yb + yrow * ND + hcol + sub * 16 + lg * 4) = o;
    }
}

extern "C" void kernel_launch(void* const* d_in, const int* in_sizes, int n_in,
                              void* d_out, int out_size, void* d_ws, size_t ws_size,
                              hipStream_t stream) {
    const float* x = (const float*)d_in[0];
    // d_in[1] = attn_mask (causal tril by construction; hardcoded)
    const float* Wqkv = (const float*)d_in[2];
    const float* Wout = (const float*)d_in[3];

    char* ws = (char*)d_ws;
    unsigned short* xb = (unsigned short*)(ws);                        // [8192][512]
    unsigned short* wqkvt = (unsigned short*)(ws + 8388608);           // [1536][512]
    unsigned short* woutt = (unsigned short*)(ws + 8388608 + 1572864); // [512][512]
    unsigned short* qbp = (unsigned short*)(ws + 10485760);            // [b,h,t,hd]
    unsigned short* kbp = (unsigned short*)(ws + 10485760 + 8388608);  // [b,h,t,hd]
    unsigned short* vtb = (unsigned short*)(ws + 10485760 + 16777216); // [b,h,hd,t]
    unsigned short* yb = xb;  // reuse x's slot after GEMM1
    float* out = (float*)d_out;

    k_prep<<<dim3(3072), dim3(256), 0, stream>>>(x, Wqkv, Wout, xb, wqkvt, woutt);
    k_gemm1<<<dim3(768), dim3(256), 0, stream>>>(xb, wqkvt, qbp, kbp, vtb, ND, 3 * ND);
    k_attn<<<dim3(1024), dim3(256), 0, stream>>>(qbp, kbp, vtb, yb);
    k_gemm2<<<dim3(512), dim3(256), 0, stream>>>(yb, woutt, out, ND, ND);
}